// Round 8
// baseline (10302.647 us; speedup 1.0000x reference)
//
#include <hip/hip_runtime.h>

#define N_USERS 200000
#define N_ITEMS 100000
#define NN      300000        // N_USERS + N_ITEMS
#define DIM     64
#define N_EDGES 9600000
#define BATCH   16384
#define RBSH    8             // 256 rows per sweep bucket
#define RB      256
#define NBK     1172          // ceil(NN / 256)
#define COLSH   9             // col bins of 512 cols for in-bucket col sort
#define NCB     586           // ceil(NN / 512)
#define CHUNK   4096          // edges per bin_sort block
#define CAPB    8960          // LDS capacity for one bucket's edges (mean 8192, +8.5 sigma)

// ---------------- bucket histogram (rows >> 8) ----------------
__global__ void hist_buckets(const int* __restrict__ rows, int* __restrict__ bcnt) {
    __shared__ int h[NBK];
    for (int i = threadIdx.x; i < NBK; i += blockDim.x) h[i] = 0;
    __syncthreads();
    int stride = gridDim.x * blockDim.x;
    for (int e = blockIdx.x * blockDim.x + threadIdx.x; e < N_EDGES; e += stride)
        atomicAdd(&h[rows[e] >> RBSH], 1);
    __syncthreads();
    for (int i = threadIdx.x; i < NBK; i += blockDim.x)
        if (h[i]) atomicAdd(&bcnt[i], h[i]);
}

// exclusive scan of NBK bucket counts (1 block, 1024 threads, 2 slots each)
__global__ __launch_bounds__(1024) void scan_buckets(const int* __restrict__ bcnt,
                                                     int* __restrict__ bst,
                                                     int* __restrict__ gfill) {
    __shared__ int s[2048];
    int tid = threadIdx.x;
    int x0 = (tid < NBK) ? bcnt[tid] : 0;
    int x1 = (tid + 1024 < NBK) ? bcnt[tid + 1024] : 0;
    s[tid] = x0; s[tid + 1024] = x1;
    __syncthreads();
    for (int off = 1; off < 2048; off <<= 1) {
        int i1 = tid + 1024;
        int a0 = (tid >= off) ? s[tid - off] : 0;
        int a1 = s[i1 - off];
        __syncthreads();
        if (tid >= off) s[tid] += a0;
        s[i1] += a1;
        __syncthreads();
    }
    if (tid < NBK)        { int v = s[tid] - x0;        bst[tid] = v;        gfill[tid] = v; }
    if (tid + 1024 < NBK) { int v = s[tid + 1024] - x1; bst[tid + 1024] = v; gfill[tid + 1024] = v; }
    if (tid == 0) bst[NBK] = N_EDGES;
}

// ---------------- pass 1: per-block counting sort into 256-row buckets ----------------
// packed edge int2: (row_local(8b) << 19 | col(19b), val)
__global__ __launch_bounds__(1024) void bin_sort(const int* __restrict__ rows,
                                                 const int* __restrict__ cols,
                                                 const float* __restrict__ vals,
                                                 int* __restrict__ gfill,
                                                 int2* __restrict__ ep) {
    __shared__ int  hist[NBK];      // count, then overwritten with local exclusive start
    __shared__ int  s[2048];
    __shared__ int  gbase[NBK];
    __shared__ int  rankc[NBK];
    __shared__ int2 st[CHUNK];
    __shared__ int  dstb[CHUNK];

    int tid = threadIdx.x;
    int e0 = blockIdx.x * CHUNK;
    int e1 = min(e0 + CHUNK, N_EDGES);
    int n  = e1 - e0;

    for (int i = tid; i < NBK; i += 1024) hist[i] = 0;
    s[tid] = 0; s[tid + 1024] = 0;
    __syncthreads();

    for (int e = e0 + tid; e < e1; e += 1024)
        atomicAdd(&hist[rows[e] >> RBSH], 1);
    __syncthreads();

    if (tid < NBK) s[tid] = hist[tid];
    if (tid + 1024 < NBK) s[tid + 1024] = hist[tid + 1024];
    __syncthreads();
    for (int off = 1; off < 2048; off <<= 1) {
        int i1 = tid + 1024;
        int a0 = (tid >= off) ? s[tid - off] : 0;
        int a1 = s[i1 - off];
        __syncthreads();
        if (tid >= off) s[tid] += a0;
        s[i1] += a1;
        __syncthreads();
    }

    for (int i = tid; i < NBK; i += 1024) {
        int cb = hist[i];
        hist[i] = s[i] - cb;                       // local exclusive start
        gbase[i] = cb ? atomicAdd(&gfill[i], cb) : 0;
        rankc[i] = 0;
    }
    __syncthreads();

    for (int e = e0 + tid; e < e1; e += 1024) {
        int r = rows[e];
        int c = cols[e];
        float v = vals[e];
        int b = r >> RBSH;
        int lr = atomicAdd(&rankc[b], 1);
        int lpos = hist[b] + lr;
        st[lpos]   = make_int2(((r & 255) << 19) | c, __float_as_int(v));
        dstb[lpos] = gbase[b] + lr;
    }
    __syncthreads();

    for (int i = tid; i < n; i += 1024)
        ep[dstb[i]] = st[i];
}

// ---------------- pass 2: in-place col-sort within each bucket (bins of 512 cols) ----------------
__global__ __launch_bounds__(1024) void col_sort(const int* __restrict__ bst,
                                                 int2* __restrict__ ep) {
    __shared__ int2 st[CAPB];
    __shared__ int  cnt[NCB];
    __shared__ int  s[1024];
    int b = blockIdx.x;
    int tid = threadIdx.x;
    int ebeg = bst[b];
    int n = bst[b + 1] - ebeg;

    for (int i = tid; i < NCB; i += 1024) cnt[i] = 0;
    for (int i = tid; i < n; i += 1024) st[i] = ep[ebeg + i];
    __syncthreads();
    for (int i = tid; i < n; i += 1024)
        atomicAdd(&cnt[(st[i].x & 0x7FFFF) >> COLSH], 1);
    __syncthreads();

    int x = (tid < NCB) ? cnt[tid] : 0;
    s[tid] = x;
    __syncthreads();
    for (int off = 1; off < 1024; off <<= 1) {
        int a = (tid >= off) ? s[tid - off] : 0;
        __syncthreads();
        if (tid >= off) s[tid] += a;
        __syncthreads();
    }
    if (tid < NCB) cnt[tid] = s[tid] - x;          // exclusive start -> ticket
    __syncthreads();

    for (int i = tid; i < n; i += 1024) {
        int bin = (st[i].x & 0x7FFFF) >> COLSH;
        int pos = atomicAdd(&cnt[bin], 1);
        ep[ebeg + pos] = st[i];
    }
}

// ---------------- SpMM: synchronized col-sweep, LDS row accumulation ----------------
// 512 persistent blocks (2/CU), each owns 256-row buckets; edges consumed in
// ascending-col order so the whole device gathers from a narrow moving band of E.
__global__ __launch_bounds__(1024) void spmm_sweep(const int* __restrict__ bst,
                                                   const int2* __restrict__ ep,
                                                   const float* __restrict__ Eu,
                                                   const float* __restrict__ Ei,
                                                   float* __restrict__ Eout) {
    __shared__ float acc[RB * DIM];                // 64 KB
    const long long* epl = (const long long*)ep;
    int tid = threadIdx.x, wid = tid >> 6, lane = tid & 63;
    float4* a4 = (float4*)acc;

    for (int b = blockIdx.x; b < NBK; b += gridDim.x) {
        for (int i = tid; i < RB * DIM / 4; i += 1024)
            a4[i] = make_float4(0.f, 0.f, 0.f, 0.f);
        __syncthreads();

        int ebeg = bst[b];
        int eend = bst[b + 1];
        for (int j0 = ebeg + wid * 4; j0 < eend; j0 += 64) {
            int j = __builtin_amdgcn_readfirstlane(j0);
            if (j + 4 <= eend) {
                long long d[4]; float x[4];
                #pragma unroll
                for (int k = 0; k < 4; ++k) d[k] = __builtin_nontemporal_load(&epl[j + k]);
                #pragma unroll
                for (int k = 0; k < 4; ++k) {
                    int c = (int)(d[k] & 0x7FFFF);
                    x[k] = (c < N_USERS) ? Eu[(size_t)c * DIM + lane]
                                         : Ei[(size_t)(c - N_USERS) * DIM + lane];
                }
                #pragma unroll
                for (int k = 0; k < 4; ++k) {
                    int rl = (int)((d[k] >> 19) & 255);
                    atomicAdd(&acc[rl * DIM + lane],
                              __int_as_float((int)(d[k] >> 32)) * x[k]);
                }
            } else {
                for (int k = 0; j + k < eend; ++k) {
                    long long d = __builtin_nontemporal_load(&epl[j + k]);
                    int c = (int)(d & 0x7FFFF);
                    float x = (c < N_USERS) ? Eu[(size_t)c * DIM + lane]
                                            : Ei[(size_t)(c - N_USERS) * DIM + lane];
                    int rl = (int)((d >> 19) & 255);
                    atomicAdd(&acc[rl * DIM + lane], __int_as_float((int)(d >> 32)) * x);
                }
            }
        }
        __syncthreads();

        int nr = min(RB, NN - (b << RBSH));
        float4* dst = (float4*)(Eout + ((size_t)b << RBSH) * DIM);
        for (int i = tid; i < nr * (DIM / 4); i += 1024) dst[i] = a4[i];
        __syncthreads();
    }
}

// ---------------- acc at the 2*BATCH target rows ----------------
__global__ void acc_init(const float* __restrict__ ue, const float* __restrict__ ie,
                         const int* __restrict__ U, const int* __restrict__ I,
                         float* __restrict__ accU, float* __restrict__ accI) {
    int t = blockIdx.x * blockDim.x + threadIdx.x;
    int b = t >> 6, d = t & 63;
    accU[t] = ue[(size_t)U[b] * DIM + d];
    accI[t] = ie[(size_t)I[b] * DIM + d];
}

__global__ void acc_add(const float* __restrict__ E, const int* __restrict__ U,
                        const int* __restrict__ I, float* __restrict__ accU,
                        float* __restrict__ accI) {
    int t = blockIdx.x * blockDim.x + threadIdx.x;
    int b = t >> 6, d = t & 63;
    accU[t] += E[(size_t)U[b] * DIM + d];
    accI[t] += E[(size_t)(N_USERS + I[b]) * DIM + d];
}

// ---------------- final: out[b] = dot(accU[b], accI[b]) / 16 ----------------
__global__ void dot_out(const float* __restrict__ accU, const float* __restrict__ accI,
                        float* __restrict__ out) {
    int t = blockIdx.x * blockDim.x + threadIdx.x;
    int b = t >> 6, lane = threadIdx.x & 63;
    float p = accU[t] * accI[t];
    #pragma unroll
    for (int off = 32; off; off >>= 1) p += __shfl_xor(p, off, 64);
    if (lane == 0) out[b] = p * (1.0f / 16.0f);
}

extern "C" void kernel_launch(void* const* d_in, const int* in_sizes, int n_in,
                              void* d_out, int out_size, void* d_ws, size_t ws_size,
                              hipStream_t stream) {
    const float* ue   = (const float*)d_in[0];
    const float* ie   = (const float*)d_in[1];
    const float* vals = (const float*)d_in[2];
    const int*   rows = (const int*)d_in[3];
    const int*   cols = (const int*)d_in[4];
    const int*   U    = (const int*)d_in[5];
    const int*   I    = (const int*)d_in[6];
    float* out = (float*)d_out;

    char* ws = (char*)d_ws;
    const size_t Ebytes  = (size_t)NN * DIM * sizeof(float);       // 76.8 MB
    const size_t EPbytes = (size_t)N_EDGES * sizeof(int2);         // 76.8 MB
    const size_t ACbytes = (size_t)BATCH * DIM * sizeof(float);    // 4.2 MB
    const size_t NBbytes = (((size_t)(NBK + 1) * sizeof(int)) + 255) & ~(size_t)255;

    size_t off = 0;
    int2*  epack = (int2*)(ws + off);  off += EPbytes;             // live all layers
    float* Ea    = (float*)(ws + off); off += Ebytes;              // L1 out, L3 out
    float* Eb    = (float*)(ws + off); off += Ebytes;              // L2 out
    float* accU  = (float*)(ws + off); off += ACbytes;
    float* accI  = (float*)(ws + off); off += ACbytes;
    int*   bcnt  = (int*)(ws + off);   off += NBbytes;
    int*   bst   = (int*)(ws + off);   off += NBbytes;
    int*   gfill = (int*)(ws + off);   off += NBbytes;

    const int nBinBlocks = (N_EDGES + CHUNK - 1) / CHUNK;          // 2344

    // --- build: bucket-sort then in-place col-sort ---
    hipMemsetAsync(bcnt, 0, (size_t)NBK * sizeof(int), stream);
    hist_buckets<<<1024, 256, 0, stream>>>(rows, bcnt);
    scan_buckets<<<1, 1024, 0, stream>>>(bcnt, bst, gfill);
    bin_sort<<<nBinBlocks, 1024, 0, stream>>>(rows, cols, vals, gfill, epack);
    col_sort<<<NBK, 1024, 0, stream>>>(bst, epack);

    // --- acc init from raw embeddings (E0 term) ---
    acc_init<<<BATCH * DIM / 256, 256, 0, stream>>>(ue, ie, U, I, accU, accI);

    // --- 3 propagation layers, synchronized col-sweep ---
    const float* EiOfs;
    spmm_sweep<<<512, 1024, 0, stream>>>(bst, epack, ue, ie, Ea);
    acc_add<<<BATCH * DIM / 256, 256, 0, stream>>>(Ea, U, I, accU, accI);

    EiOfs = Ea + (size_t)N_USERS * DIM;
    spmm_sweep<<<512, 1024, 0, stream>>>(bst, epack, Ea, EiOfs, Eb);
    acc_add<<<BATCH * DIM / 256, 256, 0, stream>>>(Eb, U, I, accU, accI);

    EiOfs = Eb + (size_t)N_USERS * DIM;
    spmm_sweep<<<512, 1024, 0, stream>>>(bst, epack, Eb, EiOfs, Ea);
    acc_add<<<BATCH * DIM / 256, 256, 0, stream>>>(Ea, U, I, accU, accI);

    dot_out<<<BATCH / 4, 256, 0, stream>>>(accU, accI, out);
}

// Round 9
// 1014.992 us; speedup vs baseline: 10.1505x; 10.1505x over previous
//
#include <hip/hip_runtime.h>

#define N_USERS 200000
#define N_ITEMS 100000
#define NN      300000        // N_USERS + N_ITEMS
#define DIM     64
#define N_EDGES 9600000
#define BATCH   16384
#define BSH2    10            // 1024 rows per bucket
#define NB2     293           // ceil(NN / 1024)
#define CHUNK2  4096          // edges per bin_sort block

// ---------------- bucket-level histogram ----------------
__global__ void hist_buckets(const int* __restrict__ rows, int* __restrict__ bcnt) {
    __shared__ int h[NB2];
    for (int i = threadIdx.x; i < NB2; i += blockDim.x) h[i] = 0;
    __syncthreads();
    int stride = gridDim.x * blockDim.x;
    for (int e = blockIdx.x * blockDim.x + threadIdx.x; e < N_EDGES; e += stride)
        atomicAdd(&h[rows[e] >> BSH2], 1);
    __syncthreads();
    for (int i = threadIdx.x; i < NB2; i += blockDim.x)
        if (h[i]) atomicAdd(&bcnt[i], h[i]);
}

// exclusive scan of 293 bucket counts; writes bstart[] and seeds gfill[]
__global__ void scan_buckets(const int* __restrict__ bcnt, int* __restrict__ bstart,
                             int* __restrict__ gfill) {
    __shared__ int s[512];
    int tid = threadIdx.x;
    int x = (tid < NB2) ? bcnt[tid] : 0;
    s[tid] = x;
    __syncthreads();
    for (int off = 1; off < 512; off <<= 1) {
        int t = (tid >= off) ? s[tid - off] : 0;
        __syncthreads();
        s[tid] += t;
        __syncthreads();
    }
    if (tid < NB2) { int v = s[tid] - x; bstart[tid] = v; gfill[tid] = v; }
    if (tid == 0) bstart[NB2] = N_EDGES;
}

// ---------------- pass 1: per-block counting sort by 1024-row bucket ----------------
// 37 KB LDS (no dstb array -> 4 blocks/CU). Flush destination recomputed via
// binary search over the 294-entry local-start array.
__global__ __launch_bounds__(256) void bin_sort(const int* __restrict__ rows,
                                                const int* __restrict__ cols,
                                                const float* __restrict__ vals,
                                                int* __restrict__ gfill,
                                                int2* __restrict__ estage) {
    __shared__ int  hist[NB2 + 1];   // counts -> local exclusive starts (+ sentinel)
    __shared__ int  sc[NB2 + 1];
    __shared__ int  gbase[NB2];
    __shared__ int  rankc[NB2];
    __shared__ int2 st[CHUNK2];

    int tid = threadIdx.x;
    int e0 = blockIdx.x * CHUNK2;
    int e1 = min(e0 + CHUNK2, N_EDGES);
    int n  = e1 - e0;

    for (int i = tid; i <= NB2; i += 256) { hist[i] = 0; sc[i] = 0; }
    __syncthreads();

    for (int e = e0 + tid; e < e1; e += 256)
        atomicAdd(&hist[rows[e] >> BSH2], 1);
    __syncthreads();

    for (int i = tid; i < NB2; i += 256) sc[i] = hist[i];
    __syncthreads();

    // inclusive Hillis-Steele scan over NB2 entries (256 threads own 2 slots each)
    for (int off = 1; off < NB2; off <<= 1) {
        int i0 = tid, i1 = tid + 256;
        int a0 = 0, a1 = 0;
        if (i0 < NB2 && i0 >= off) a0 = sc[i0 - off];
        if (i1 < NB2 && i1 >= off) a1 = sc[i1 - off];
        __syncthreads();
        if (i0 < NB2 && i0 >= off) sc[i0] += a0;
        if (i1 < NB2 && i1 >= off) sc[i1] += a1;
        __syncthreads();
    }

    for (int b = tid; b < NB2; b += 256) {
        int cb = hist[b];
        hist[b] = sc[b] - cb;                     // local exclusive start
        gbase[b] = cb ? atomicAdd(&gfill[b], cb) : 0;
        rankc[b] = 0;
    }
    if (tid == 0) hist[NB2] = CHUNK2 + 1;         // sentinel > any i
    __syncthreads();

    // rank + reorder into LDS (bucket-grouped order)
    for (int e = e0 + tid; e < e1; e += 256) {
        int r = rows[e];
        int c = cols[e];
        float v = vals[e];
        int b = r >> BSH2;
        int lr = atomicAdd(&rankc[b], 1);
        st[hist[b] + lr] = make_int2(((r & 1023) << 19) | c, __float_as_int(v));
    }
    __syncthreads();

    // flush: bucket of slot i via binary search (last b with hist[b] <= i)
    for (int i = tid; i < n; i += 256) {
        int lo = 0, hi = NB2;
        while (hi - lo > 1) {
            int mid = (lo + hi) >> 1;
            if (hist[mid] <= i) lo = mid; else hi = mid;
        }
        estage[gbase[lo] + (i - hist[lo])] = st[i];
    }
}

// ---------------- pass 2: one block per bucket; builds rowptr, ticket-scatters ----------------
__global__ __launch_bounds__(1024) void row_scatter(const int* __restrict__ bstart,
                                                    const int2* __restrict__ estage,
                                                    int2* __restrict__ epack,
                                                    int* __restrict__ rowptr) {
    __shared__ int lcnt[1024];
    __shared__ int s[1024];
    int b = blockIdx.x;
    int r0 = b << BSH2;
    int nr = min(1024, NN - r0);
    int tid = threadIdx.x;
    lcnt[tid] = 0;
    __syncthreads();

    int ebeg = bstart[b];
    int eend = bstart[b + 1];
    for (int e = ebeg + tid; e < eend; e += 1024)
        atomicAdd(&lcnt[((unsigned)estage[e].x) >> 19], 1);
    __syncthreads();

    int x = lcnt[tid];
    s[tid] = x;
    __syncthreads();
    for (int off = 1; off < 1024; off <<= 1) {
        int t = (tid >= off) ? s[tid - off] : 0;
        __syncthreads();
        s[tid] += t;
        __syncthreads();
    }
    int myptr = ebeg + s[tid] - x;
    if (tid < nr) rowptr[r0 + tid] = myptr;
    lcnt[tid] = myptr;                 // reuse as ticket
    __syncthreads();

    for (int e = ebeg + tid; e < eend; e += 1024) {
        int2 ed = estage[e];
        int rl = ((unsigned)ed.x) >> 19;
        int pos = atomicAdd(&lcnt[rl], 1);
        epack[pos] = make_int2(ed.x & 0x7FFFF, ed.y);
    }
    if (b == 0 && tid == 0) rowptr[NN] = N_EDGES;
}

// ---------------- shared row-dot: 8-wide unroll, nt edge-stream loads ----------------
// Eu: base for cols < N_USERS; EiAdj: (item base - N_USERS*DIM) so both index by c.
__device__ __forceinline__ float row_dot(const int2* __restrict__ ep, int beg, int end,
                                         const float* __restrict__ Eu,
                                         const float* __restrict__ EiAdj, int lane) {
    const long long* epl = (const long long*)ep;
    float acc = 0.f;
    int j = beg;
    int jend8 = beg + ((end - beg) & ~7);
    for (; j < jend8; j += 8) {
        long long d[8];
        #pragma unroll
        for (int k = 0; k < 8; ++k) d[k] = __builtin_nontemporal_load(&epl[j + k]);
        float x[8];
        #pragma unroll
        for (int k = 0; k < 8; ++k) {
            int c = (int)(d[k] & 0x7FFFF);
            const float* base = (c < N_USERS) ? Eu : EiAdj;
            x[k] = base[(size_t)c * DIM + lane];
        }
        #pragma unroll
        for (int k = 0; k < 8; ++k)
            acc = __builtin_fmaf(__int_as_float((int)(d[k] >> 32)), x[k], acc);
    }
    if (j + 4 <= end) {
        long long d[4];
        #pragma unroll
        for (int k = 0; k < 4; ++k) d[k] = __builtin_nontemporal_load(&epl[j + k]);
        float x[4];
        #pragma unroll
        for (int k = 0; k < 4; ++k) {
            int c = (int)(d[k] & 0x7FFFF);
            const float* base = (c < N_USERS) ? Eu : EiAdj;
            x[k] = base[(size_t)c * DIM + lane];
        }
        #pragma unroll
        for (int k = 0; k < 4; ++k)
            acc = __builtin_fmaf(__int_as_float((int)(d[k] >> 32)), x[k], acc);
        j += 4;
    }
    for (; j < end; ++j) {
        long long d = __builtin_nontemporal_load(&epl[j]);
        int c = (int)(d & 0x7FFFF);
        const float* base = (c < N_USERS) ? Eu : EiAdj;
        acc = __builtin_fmaf(__int_as_float((int)(d >> 32)),
                             base[(size_t)c * DIM + lane], acc);
    }
    return acc;
}

// ---------------- SpMM: one wave per row, lane = dim ----------------
__global__ void spmm_csr(const int* __restrict__ rowptr, const int2* __restrict__ ep,
                         const float* __restrict__ Eu, const float* __restrict__ EiAdj,
                         float* __restrict__ Eout) {
    int lane = threadIdx.x & 63;
    int w = (int)((blockIdx.x * (size_t)blockDim.x + threadIdx.x) >> 6);
    int row = __builtin_amdgcn_readfirstlane(w);
    if (row >= NN) return;
    int beg = rowptr[row];
    int end = rowptr[row + 1];
    float acc = row_dot(ep, beg, end, Eu, EiAdj, lane);
    __builtin_nontemporal_store(acc, &Eout[(size_t)row * DIM + lane]);
}

// ---------------- layer 3: SpMM only at the 2*BATCH target rows, fused acc ----------------
__global__ void spmm_target(const int* __restrict__ rowptr, const int2* __restrict__ ep,
                            const float* __restrict__ Eu, const float* __restrict__ EiAdj,
                            const int* __restrict__ U, const int* __restrict__ I,
                            float* __restrict__ accU, float* __restrict__ accI) {
    int lane = threadIdx.x & 63;
    int w = (int)((blockIdx.x * (size_t)blockDim.x + threadIdx.x) >> 6);
    if (w >= 2 * BATCH) return;
    int row;
    float* accp;
    if (w < BATCH) { row = U[w];                   accp = accU + (size_t)w * DIM; }
    else           { row = N_USERS + I[w - BATCH]; accp = accI + (size_t)(w - BATCH) * DIM; }
    row = __builtin_amdgcn_readfirstlane(row);
    int beg = rowptr[row];
    int end = rowptr[row + 1];
    float acc = row_dot(ep, beg, end, Eu, EiAdj, lane);
    accp[lane] += acc;
}

// ---------------- acc at the 2*BATCH target rows ----------------
__global__ void acc_init(const float* __restrict__ ue, const float* __restrict__ ie,
                         const int* __restrict__ U, const int* __restrict__ I,
                         float* __restrict__ accU, float* __restrict__ accI) {
    int t = blockIdx.x * blockDim.x + threadIdx.x;
    int b = t >> 6, d = t & 63;
    accU[t] = ue[(size_t)U[b] * DIM + d];
    accI[t] = ie[(size_t)I[b] * DIM + d];
}

__global__ void acc_add(const float* __restrict__ E, const int* __restrict__ U,
                        const int* __restrict__ I, float* __restrict__ accU,
                        float* __restrict__ accI) {
    int t = blockIdx.x * blockDim.x + threadIdx.x;
    int b = t >> 6, d = t & 63;
    accU[t] += E[(size_t)U[b] * DIM + d];
    accI[t] += E[(size_t)(N_USERS + I[b]) * DIM + d];
}

// ---------------- final: out[b] = dot(accU[b], accI[b]) / 16 ----------------
__global__ void dot_out(const float* __restrict__ accU, const float* __restrict__ accI,
                        float* __restrict__ out) {
    int t = blockIdx.x * blockDim.x + threadIdx.x;
    int b = t >> 6, lane = threadIdx.x & 63;
    float p = accU[t] * accI[t];
    #pragma unroll
    for (int off = 32; off; off >>= 1) p += __shfl_xor(p, off, 64);
    if (lane == 0) out[b] = p * (1.0f / 16.0f);
}

extern "C" void kernel_launch(void* const* d_in, const int* in_sizes, int n_in,
                              void* d_out, int out_size, void* d_ws, size_t ws_size,
                              hipStream_t stream) {
    const float* ue   = (const float*)d_in[0];
    const float* ie   = (const float*)d_in[1];
    const float* vals = (const float*)d_in[2];
    const int*   rows = (const int*)d_in[3];
    const int*   cols = (const int*)d_in[4];
    const int*   U    = (const int*)d_in[5];
    const int*   I    = (const int*)d_in[6];
    float* out = (float*)d_out;

    char* ws = (char*)d_ws;
    const size_t Ebytes  = (size_t)NN * DIM * sizeof(float);       // 76.8 MB
    const size_t EPbytes = (size_t)N_EDGES * sizeof(int2);         // 76.8 MB
    const size_t ACbytes = (size_t)BATCH * DIM * sizeof(float);    // 4.2 MB
    const size_t RPbytes = ((size_t)(NN + 1) * sizeof(int) + 255) & ~(size_t)255;
    const size_t NBbytes = (((size_t)(NB2 + 1) * sizeof(int)) + 255) & ~(size_t)255;

    size_t off = 0;
    float* Ea     = (float*)(ws + off); off += Ebytes;             // aliased by estage pre-spmm1
    float* Eb     = (float*)(ws + off); off += Ebytes;
    int2*  epack  = (int2*)(ws + off);  off += EPbytes;
    float* accU   = (float*)(ws + off); off += ACbytes;
    float* accI   = (float*)(ws + off); off += ACbytes;
    int*   rowptr = (int*)(ws + off);   off += RPbytes;
    int*   bcnt   = (int*)(ws + off);   off += NBbytes;
    int*   bstart = (int*)(ws + off);   off += NBbytes;
    int*   gfill  = (int*)(ws + off);   off += NBbytes;

    // edge staging (8 B/edge) aliases Ea (dead before spmm layer 1 writes it)
    int2* estage = (int2*)Ea;

    const int nBinBlocks = (N_EDGES + CHUNK2 - 1) / CHUNK2;        // 2344

    // --- build CSR ---
    hipMemsetAsync(bcnt, 0, (size_t)(NB2 + 1) * sizeof(int), stream);
    hist_buckets<<<1024, 256, 0, stream>>>(rows, bcnt);
    scan_buckets<<<1, 512, 0, stream>>>(bcnt, bstart, gfill);
    bin_sort<<<nBinBlocks, 256, 0, stream>>>(rows, cols, vals, gfill, estage);
    row_scatter<<<NB2, 1024, 0, stream>>>(bstart, estage, epack, rowptr);

    // --- E0 term at targets (reads raw embeddings; no copy_init) ---
    acc_init<<<BATCH * DIM / 256, 256, 0, stream>>>(ue, ie, U, I, accU, accI);

    const int spmmBlocks = (NN * 64 + 255) / 256;                  // 1 wave per row
    const float* ieAdj = ie - (size_t)N_USERS * DIM;               // never deref'd for c<N_USERS

    // layer 1: gather from raw ue/ie
    spmm_csr<<<spmmBlocks, 256, 0, stream>>>(rowptr, epack, ue, ieAdj, Ea);
    acc_add<<<BATCH * DIM / 256, 256, 0, stream>>>(Ea, U, I, accU, accI);

    // layer 2: gather from Ea (concat layout -> both bases identical)
    spmm_csr<<<spmmBlocks, 256, 0, stream>>>(rowptr, epack, Ea, Ea, Eb);
    acc_add<<<BATCH * DIM / 256, 256, 0, stream>>>(Eb, U, I, accU, accI);

    // layer 3: only at target rows, fused accumulate
    spmm_target<<<2 * BATCH * 64 / 256, 256, 0, stream>>>(rowptr, epack, Eb, Eb, U, I, accU, accI);

    dot_out<<<BATCH / 4, 256, 0, stream>>>(accU, accI, out);
}

// Round 10
// 716.151 us; speedup vs baseline: 14.3861x; 1.4173x over previous
//
#include <hip/hip_runtime.h>

#define N_USERS 200000
#define N_ITEMS 100000
#define NN      300000        // N_USERS + N_ITEMS
#define DIM     64
#define N_EDGES 9600000
#define BATCH   16384
#define BSH2    10            // 1024 rows per bucket
#define NB2     293           // ceil(NN / 1024)
#define CHUNK2  4096          // edges per bin_sort block

// ---------------- bf16 helpers (RNE) ----------------
__device__ __forceinline__ unsigned short f2bf(float f) {
    unsigned b = __float_as_uint(f);
    return (unsigned short)((b + 0x7FFF + ((b >> 16) & 1)) >> 16);
}
__device__ __forceinline__ float bf2f(unsigned short u) {
    return __uint_as_float((unsigned)u << 16);
}

// ---------------- E0 -> bf16 concat table ----------------
__global__ void to_bf16(const float* __restrict__ ue, const float* __restrict__ ie,
                        unsigned short* __restrict__ E) {
    const size_t nU = (size_t)N_USERS * DIM / 4;
    const size_t nT = (size_t)NN * DIM / 4;
    const float4* u4 = (const float4*)ue;
    const float4* i4 = (const float4*)ie;
    ushort4* E4 = (ushort4*)E;
    size_t stride = (size_t)gridDim.x * blockDim.x;
    for (size_t k = (size_t)blockIdx.x * blockDim.x + threadIdx.x; k < nT; k += stride) {
        float4 v = (k < nU) ? u4[k] : i4[k - nU];
        ushort4 o;
        o.x = f2bf(v.x); o.y = f2bf(v.y); o.z = f2bf(v.z); o.w = f2bf(v.w);
        E4[k] = o;
    }
}

// ---------------- bucket-level histogram ----------------
__global__ void hist_buckets(const int* __restrict__ rows, int* __restrict__ bcnt) {
    __shared__ int h[NB2];
    for (int i = threadIdx.x; i < NB2; i += blockDim.x) h[i] = 0;
    __syncthreads();
    int stride = gridDim.x * blockDim.x;
    for (int e = blockIdx.x * blockDim.x + threadIdx.x; e < N_EDGES; e += stride)
        atomicAdd(&h[rows[e] >> BSH2], 1);
    __syncthreads();
    for (int i = threadIdx.x; i < NB2; i += blockDim.x)
        if (h[i]) atomicAdd(&bcnt[i], h[i]);
}

// exclusive scan of 293 bucket counts; writes bstart[] and seeds gfill[]
__global__ void scan_buckets(const int* __restrict__ bcnt, int* __restrict__ bstart,
                             int* __restrict__ gfill) {
    __shared__ int s[512];
    int tid = threadIdx.x;
    int x = (tid < NB2) ? bcnt[tid] : 0;
    s[tid] = x;
    __syncthreads();
    for (int off = 1; off < 512; off <<= 1) {
        int t = (tid >= off) ? s[tid - off] : 0;
        __syncthreads();
        s[tid] += t;
        __syncthreads();
    }
    if (tid < NB2) { int v = s[tid] - x; bstart[tid] = v; gfill[tid] = v; }
    if (tid == 0) bstart[NB2] = N_EDGES;
}

// ---------------- pass 1: per-block counting sort by 1024-row bucket ----------------
__global__ __launch_bounds__(256) void bin_sort(const int* __restrict__ rows,
                                                const int* __restrict__ cols,
                                                const float* __restrict__ vals,
                                                int* __restrict__ gfill,
                                                int2* __restrict__ estage) {
    __shared__ int  hist[NB2 + 1];   // counts -> local exclusive starts (+ sentinel)
    __shared__ int  sc[NB2 + 1];
    __shared__ int  gbase[NB2];
    __shared__ int  rankc[NB2];
    __shared__ int2 st[CHUNK2];

    int tid = threadIdx.x;
    int e0 = blockIdx.x * CHUNK2;
    int e1 = min(e0 + CHUNK2, N_EDGES);
    int n  = e1 - e0;

    for (int i = tid; i <= NB2; i += 256) { hist[i] = 0; sc[i] = 0; }
    __syncthreads();

    for (int e = e0 + tid; e < e1; e += 256)
        atomicAdd(&hist[rows[e] >> BSH2], 1);
    __syncthreads();

    for (int i = tid; i < NB2; i += 256) sc[i] = hist[i];
    __syncthreads();

    for (int off = 1; off < NB2; off <<= 1) {
        int i0 = tid, i1 = tid + 256;
        int a0 = 0, a1 = 0;
        if (i0 < NB2 && i0 >= off) a0 = sc[i0 - off];
        if (i1 < NB2 && i1 >= off) a1 = sc[i1 - off];
        __syncthreads();
        if (i0 < NB2 && i0 >= off) sc[i0] += a0;
        if (i1 < NB2 && i1 >= off) sc[i1] += a1;
        __syncthreads();
    }

    for (int b = tid; b < NB2; b += 256) {
        int cb = hist[b];
        hist[b] = sc[b] - cb;                     // local exclusive start
        gbase[b] = cb ? atomicAdd(&gfill[b], cb) : 0;
        rankc[b] = 0;
    }
    if (tid == 0) hist[NB2] = CHUNK2 + 1;         // sentinel > any i
    __syncthreads();

    for (int e = e0 + tid; e < e1; e += 256) {
        int r = rows[e];
        int c = cols[e];
        float v = vals[e];
        int b = r >> BSH2;
        int lr = atomicAdd(&rankc[b], 1);
        st[hist[b] + lr] = make_int2(((r & 1023) << 19) | c, __float_as_int(v));
    }
    __syncthreads();

    for (int i = tid; i < n; i += 256) {
        int lo = 0, hi = NB2;
        while (hi - lo > 1) {
            int mid = (lo + hi) >> 1;
            if (hist[mid] <= i) lo = mid; else hi = mid;
        }
        estage[gbase[lo] + (i - hist[lo])] = st[i];
    }
}

// ---------------- pass 2: one block per bucket; builds rowptr, ticket-scatters ----------------
__global__ __launch_bounds__(1024) void row_scatter(const int* __restrict__ bstart,
                                                    const int2* __restrict__ estage,
                                                    int2* __restrict__ epack,
                                                    int* __restrict__ rowptr) {
    __shared__ int lcnt[1024];
    __shared__ int s[1024];
    int b = blockIdx.x;
    int r0 = b << BSH2;
    int nr = min(1024, NN - r0);
    int tid = threadIdx.x;
    lcnt[tid] = 0;
    __syncthreads();

    int ebeg = bstart[b];
    int eend = bstart[b + 1];
    for (int e = ebeg + tid; e < eend; e += 1024)
        atomicAdd(&lcnt[((unsigned)estage[e].x) >> 19], 1);
    __syncthreads();

    int x = lcnt[tid];
    s[tid] = x;
    __syncthreads();
    for (int off = 1; off < 1024; off <<= 1) {
        int t = (tid >= off) ? s[tid - off] : 0;
        __syncthreads();
        s[tid] += t;
        __syncthreads();
    }
    int myptr = ebeg + s[tid] - x;
    if (tid < nr) rowptr[r0 + tid] = myptr;
    lcnt[tid] = myptr;                 // reuse as ticket
    __syncthreads();

    for (int e = ebeg + tid; e < eend; e += 1024) {
        int2 ed = estage[e];
        int rl = ((unsigned)ed.x) >> 19;
        int pos = atomicAdd(&lcnt[rl], 1);
        epack[pos] = make_int2(ed.x & 0x7FFFF, ed.y);
    }
    if (b == 0 && tid == 0) rowptr[NN] = N_EDGES;
}

// ---------------- shared row-dot: 8-wide unroll, bf16 gather, f32 accumulate ----------------
__device__ __forceinline__ float row_dot(const int2* __restrict__ ep, int beg, int end,
                                         const unsigned short* __restrict__ E, int lane) {
    const long long* epl = (const long long*)ep;
    float acc = 0.f;
    int j = beg;
    int jend8 = beg + ((end - beg) & ~7);
    for (; j < jend8; j += 8) {
        long long d[8];
        #pragma unroll
        for (int k = 0; k < 8; ++k) d[k] = __builtin_nontemporal_load(&epl[j + k]);
        float x[8];
        #pragma unroll
        for (int k = 0; k < 8; ++k)
            x[k] = bf2f(E[(size_t)(int)(d[k] & 0x7FFFF) * DIM + lane]);
        #pragma unroll
        for (int k = 0; k < 8; ++k)
            acc = __builtin_fmaf(__int_as_float((int)(d[k] >> 32)), x[k], acc);
    }
    if (j + 4 <= end) {
        long long d[4];
        #pragma unroll
        for (int k = 0; k < 4; ++k) d[k] = __builtin_nontemporal_load(&epl[j + k]);
        float x[4];
        #pragma unroll
        for (int k = 0; k < 4; ++k)
            x[k] = bf2f(E[(size_t)(int)(d[k] & 0x7FFFF) * DIM + lane]);
        #pragma unroll
        for (int k = 0; k < 4; ++k)
            acc = __builtin_fmaf(__int_as_float((int)(d[k] >> 32)), x[k], acc);
        j += 4;
    }
    for (; j < end; ++j) {
        long long d = __builtin_nontemporal_load(&epl[j]);
        acc = __builtin_fmaf(__int_as_float((int)(d >> 32)),
                             bf2f(E[(size_t)(int)(d & 0x7FFFF) * DIM + lane]), acc);
    }
    return acc;
}

// ---------------- SpMM: one wave per row, lane = dim, bf16 in/out ----------------
__global__ void spmm_csr(const int* __restrict__ rowptr, const int2* __restrict__ ep,
                         const unsigned short* __restrict__ Ein,
                         unsigned short* __restrict__ Eout) {
    int lane = threadIdx.x & 63;
    int w = (int)((blockIdx.x * (size_t)blockDim.x + threadIdx.x) >> 6);
    int row = __builtin_amdgcn_readfirstlane(w);
    if (row >= NN) return;
    int beg = rowptr[row];
    int end = rowptr[row + 1];
    float acc = row_dot(ep, beg, end, Ein, lane);
    __builtin_nontemporal_store(f2bf(acc), &Eout[(size_t)row * DIM + lane]);
}

// ---------------- layer 3: SpMM only at the 2*BATCH target rows, fused acc ----------------
__global__ void spmm_target(const int* __restrict__ rowptr, const int2* __restrict__ ep,
                            const unsigned short* __restrict__ Ein,
                            const int* __restrict__ U, const int* __restrict__ I,
                            float* __restrict__ accU, float* __restrict__ accI) {
    int lane = threadIdx.x & 63;
    int w = (int)((blockIdx.x * (size_t)blockDim.x + threadIdx.x) >> 6);
    if (w >= 2 * BATCH) return;
    int row;
    float* accp;
    if (w < BATCH) { row = U[w];                   accp = accU + (size_t)w * DIM; }
    else           { row = N_USERS + I[w - BATCH]; accp = accI + (size_t)(w - BATCH) * DIM; }
    row = __builtin_amdgcn_readfirstlane(row);
    int beg = rowptr[row];
    int end = rowptr[row + 1];
    float acc = row_dot(ep, beg, end, Ein, lane);
    accp[lane] += acc;
}

// ---------------- acc at the 2*BATCH target rows ----------------
__global__ void acc_init(const float* __restrict__ ue, const float* __restrict__ ie,
                         const int* __restrict__ U, const int* __restrict__ I,
                         float* __restrict__ accU, float* __restrict__ accI) {
    int t = blockIdx.x * blockDim.x + threadIdx.x;
    int b = t >> 6, d = t & 63;
    accU[t] = ue[(size_t)U[b] * DIM + d];
    accI[t] = ie[(size_t)I[b] * DIM + d];
}

__global__ void acc_add(const unsigned short* __restrict__ E, const int* __restrict__ U,
                        const int* __restrict__ I, float* __restrict__ accU,
                        float* __restrict__ accI) {
    int t = blockIdx.x * blockDim.x + threadIdx.x;
    int b = t >> 6, d = t & 63;
    accU[t] += bf2f(E[(size_t)U[b] * DIM + d]);
    accI[t] += bf2f(E[(size_t)(N_USERS + I[b]) * DIM + d]);
}

// ---------------- final: out[b] = dot(accU[b], accI[b]) / 16 ----------------
__global__ void dot_out(const float* __restrict__ accU, const float* __restrict__ accI,
                        float* __restrict__ out) {
    int t = blockIdx.x * blockDim.x + threadIdx.x;
    int b = t >> 6, lane = threadIdx.x & 63;
    float p = accU[t] * accI[t];
    #pragma unroll
    for (int off = 32; off; off >>= 1) p += __shfl_xor(p, off, 64);
    if (lane == 0) out[b] = p * (1.0f / 16.0f);
}

extern "C" void kernel_launch(void* const* d_in, const int* in_sizes, int n_in,
                              void* d_out, int out_size, void* d_ws, size_t ws_size,
                              hipStream_t stream) {
    const float* ue   = (const float*)d_in[0];
    const float* ie   = (const float*)d_in[1];
    const float* vals = (const float*)d_in[2];
    const int*   rows = (const int*)d_in[3];
    const int*   cols = (const int*)d_in[4];
    const int*   U    = (const int*)d_in[5];
    const int*   I    = (const int*)d_in[6];
    float* out = (float*)d_out;

    char* ws = (char*)d_ws;
    const size_t EPbytes = (size_t)N_EDGES * sizeof(int2);            // 76.8 MB
    const size_t EBbytes = (size_t)NN * DIM * sizeof(unsigned short); // 38.4 MB
    const size_t ACbytes = (size_t)BATCH * DIM * sizeof(float);       // 4.2 MB
    const size_t RPbytes = ((size_t)(NN + 1) * sizeof(int) + 255) & ~(size_t)255;
    const size_t NBbytes = (((size_t)(NB2 + 1) * sizeof(int)) + 255) & ~(size_t)255;

    size_t off = 0;
    int2*  epack  = (int2*)(ws + off);           off += EPbytes;
    unsigned short* Ebf_a = (unsigned short*)(ws + off); off += EBbytes;  // aliased by estage pre-to_bf16
    unsigned short* Ebf_b = (unsigned short*)(ws + off); off += EBbytes;
    float* accU   = (float*)(ws + off); off += ACbytes;
    float* accI   = (float*)(ws + off); off += ACbytes;
    int*   rowptr = (int*)(ws + off);   off += RPbytes;
    int*   bcnt   = (int*)(ws + off);   off += NBbytes;
    int*   bstart = (int*)(ws + off);   off += NBbytes;
    int*   gfill  = (int*)(ws + off);   off += NBbytes;

    // edge staging (8 B/edge) aliases Ebf_a+Ebf_b region (dead before to_bf16 runs)
    int2* estage = (int2*)Ebf_a;

    const int nBinBlocks = (N_EDGES + CHUNK2 - 1) / CHUNK2;           // 2344

    // --- build CSR ---
    hipMemsetAsync(bcnt, 0, (size_t)(NB2 + 1) * sizeof(int), stream);
    hist_buckets<<<1024, 256, 0, stream>>>(rows, bcnt);
    scan_buckets<<<1, 512, 0, stream>>>(bcnt, bstart, gfill);
    bin_sort<<<nBinBlocks, 256, 0, stream>>>(rows, cols, vals, gfill, estage);
    row_scatter<<<NB2, 1024, 0, stream>>>(bstart, estage, epack, rowptr);

    // --- bf16 embedding table (after estage is dead) + exact-f32 E0 term ---
    to_bf16<<<2048, 256, 0, stream>>>(ue, ie, Ebf_a);
    acc_init<<<BATCH * DIM / 256, 256, 0, stream>>>(ue, ie, U, I, accU, accI);

    const int spmmBlocks = (NN * 64 + 255) / 256;                     // 1 wave per row

    // layer 1: Ebf_a -> Ebf_b
    spmm_csr<<<spmmBlocks, 256, 0, stream>>>(rowptr, epack, Ebf_a, Ebf_b);
    acc_add<<<BATCH * DIM / 256, 256, 0, stream>>>(Ebf_b, U, I, accU, accI);

    // layer 2: Ebf_b -> Ebf_a
    spmm_csr<<<spmmBlocks, 256, 0, stream>>>(rowptr, epack, Ebf_b, Ebf_a);
    acc_add<<<BATCH * DIM / 256, 256, 0, stream>>>(Ebf_a, U, I, accU, accI);

    // layer 3: only at target rows, fused accumulate
    spmm_target<<<2 * BATCH * 64 / 256, 256, 0, stream>>>(rowptr, epack, Ebf_a, U, I, accU, accI);

    dot_out<<<BATCH / 4, 256, 0, stream>>>(accU, accI, out);
}

// Round 11
// 715.239 us; speedup vs baseline: 14.4045x; 1.0013x over previous
//
#include <hip/hip_runtime.h>

#define N_USERS 200000
#define N_ITEMS 100000
#define NN      300000        // N_USERS + N_ITEMS
#define DIM     64
#define N_EDGES 9600000
#define BATCH   16384
#define BSH2    10            // 1024 rows per bucket
#define NB2     293           // ceil(NN / 1024)
#define CHUNK2  4096          // edges per bin_sort block
#define FP8SCALE   32768.0f   // 2^15: max|E1|*S ~ 92, max|E2|*S ~ 4  (e4m3 max 448)
#define FP8DESCALE (1.0f / 32768.0f)

// ---------------- bf16 helpers (RNE) ----------------
__device__ __forceinline__ unsigned short f2bf(float f) {
    unsigned b = __float_as_uint(f);
    return (unsigned short)((b + 0x7FFF + ((b >> 16) & 1)) >> 16);
}
__device__ __forceinline__ float bf2f(unsigned short u) {
    return __uint_as_float((unsigned)u << 16);
}
// ---------------- fp8 e4m3 helpers (HW convert) ----------------
__device__ __forceinline__ unsigned char f2fp8(float scaled) {
    float c = fminf(fmaxf(scaled, -440.f), 440.f);
    int pk = __builtin_amdgcn_cvt_pk_fp8_f32(c, c, 0, false);
    return (unsigned char)(pk & 0xFF);
}
__device__ __forceinline__ float fp82f(unsigned char b) {
    return __builtin_amdgcn_cvt_f32_fp8((int)b, 0);
}

// ---------------- E0 -> bf16 concat table ----------------
__global__ void to_bf16(const float* __restrict__ ue, const float* __restrict__ ie,
                        unsigned short* __restrict__ E) {
    const size_t nU = (size_t)N_USERS * DIM / 4;
    const size_t nT = (size_t)NN * DIM / 4;
    const float4* u4 = (const float4*)ue;
    const float4* i4 = (const float4*)ie;
    ushort4* E4 = (ushort4*)E;
    size_t stride = (size_t)gridDim.x * blockDim.x;
    for (size_t k = (size_t)blockIdx.x * blockDim.x + threadIdx.x; k < nT; k += stride) {
        float4 v = (k < nU) ? u4[k] : i4[k - nU];
        ushort4 o;
        o.x = f2bf(v.x); o.y = f2bf(v.y); o.z = f2bf(v.z); o.w = f2bf(v.w);
        E4[k] = o;
    }
}

// ---------------- bucket-level histogram ----------------
__global__ void hist_buckets(const int* __restrict__ rows, int* __restrict__ bcnt) {
    __shared__ int h[NB2];
    for (int i = threadIdx.x; i < NB2; i += blockDim.x) h[i] = 0;
    __syncthreads();
    int stride = gridDim.x * blockDim.x;
    for (int e = blockIdx.x * blockDim.x + threadIdx.x; e < N_EDGES; e += stride)
        atomicAdd(&h[rows[e] >> BSH2], 1);
    __syncthreads();
    for (int i = threadIdx.x; i < NB2; i += blockDim.x)
        if (h[i]) atomicAdd(&bcnt[i], h[i]);
}

// exclusive scan of 293 bucket counts; writes bstart[] and seeds gfill[]
__global__ void scan_buckets(const int* __restrict__ bcnt, int* __restrict__ bstart,
                             int* __restrict__ gfill) {
    __shared__ int s[512];
    int tid = threadIdx.x;
    int x = (tid < NB2) ? bcnt[tid] : 0;
    s[tid] = x;
    __syncthreads();
    for (int off = 1; off < 512; off <<= 1) {
        int t = (tid >= off) ? s[tid - off] : 0;
        __syncthreads();
        s[tid] += t;
        __syncthreads();
    }
    if (tid < NB2) { int v = s[tid] - x; bstart[tid] = v; gfill[tid] = v; }
    if (tid == 0) bstart[NB2] = N_EDGES;
}

// ---------------- pass 1: per-block counting sort by 1024-row bucket ----------------
__global__ __launch_bounds__(256) void bin_sort(const int* __restrict__ rows,
                                                const int* __restrict__ cols,
                                                const float* __restrict__ vals,
                                                int* __restrict__ gfill,
                                                int2* __restrict__ estage) {
    __shared__ int  hist[NB2 + 1];   // counts -> local exclusive starts (+ sentinel)
    __shared__ int  sc[NB2 + 1];
    __shared__ int  gbase[NB2];
    __shared__ int  rankc[NB2];
    __shared__ int2 st[CHUNK2];

    int tid = threadIdx.x;
    int e0 = blockIdx.x * CHUNK2;
    int e1 = min(e0 + CHUNK2, N_EDGES);
    int n  = e1 - e0;

    for (int i = tid; i <= NB2; i += 256) { hist[i] = 0; sc[i] = 0; }
    __syncthreads();

    for (int e = e0 + tid; e < e1; e += 256)
        atomicAdd(&hist[rows[e] >> BSH2], 1);
    __syncthreads();

    for (int i = tid; i < NB2; i += 256) sc[i] = hist[i];
    __syncthreads();

    for (int off = 1; off < NB2; off <<= 1) {
        int i0 = tid, i1 = tid + 256;
        int a0 = 0, a1 = 0;
        if (i0 < NB2 && i0 >= off) a0 = sc[i0 - off];
        if (i1 < NB2 && i1 >= off) a1 = sc[i1 - off];
        __syncthreads();
        if (i0 < NB2 && i0 >= off) sc[i0] += a0;
        if (i1 < NB2 && i1 >= off) sc[i1] += a1;
        __syncthreads();
    }

    for (int b = tid; b < NB2; b += 256) {
        int cb = hist[b];
        hist[b] = sc[b] - cb;                     // local exclusive start
        gbase[b] = cb ? atomicAdd(&gfill[b], cb) : 0;
        rankc[b] = 0;
    }
    if (tid == 0) hist[NB2] = CHUNK2 + 1;         // sentinel > any i
    __syncthreads();

    for (int e = e0 + tid; e < e1; e += 256) {
        int r = rows[e];
        int c = cols[e];
        float v = vals[e];
        int b = r >> BSH2;
        int lr = atomicAdd(&rankc[b], 1);
        st[hist[b] + lr] = make_int2(((r & 1023) << 19) | c, __float_as_int(v));
    }
    __syncthreads();

    for (int i = tid; i < n; i += 256) {
        int lo = 0, hi = NB2;
        while (hi - lo > 1) {
            int mid = (lo + hi) >> 1;
            if (hist[mid] <= i) lo = mid; else hi = mid;
        }
        estage[gbase[lo] + (i - hist[lo])] = st[i];
    }
}

// ---------------- pass 2: one block per bucket; builds rowptr, ticket-scatters ----------------
__global__ __launch_bounds__(1024) void row_scatter(const int* __restrict__ bstart,
                                                    const int2* __restrict__ estage,
                                                    int2* __restrict__ epack,
                                                    int* __restrict__ rowptr) {
    __shared__ int lcnt[1024];
    __shared__ int s[1024];
    int b = blockIdx.x;
    int r0 = b << BSH2;
    int nr = min(1024, NN - r0);
    int tid = threadIdx.x;
    lcnt[tid] = 0;
    __syncthreads();

    int ebeg = bstart[b];
    int eend = bstart[b + 1];
    for (int e = ebeg + tid; e < eend; e += 1024)
        atomicAdd(&lcnt[((unsigned)estage[e].x) >> 19], 1);
    __syncthreads();

    int x = lcnt[tid];
    s[tid] = x;
    __syncthreads();
    for (int off = 1; off < 1024; off <<= 1) {
        int t = (tid >= off) ? s[tid - off] : 0;
        __syncthreads();
        s[tid] += t;
        __syncthreads();
    }
    int myptr = ebeg + s[tid] - x;
    if (tid < nr) rowptr[r0 + tid] = myptr;
    lcnt[tid] = myptr;                 // reuse as ticket
    __syncthreads();

    for (int e = ebeg + tid; e < eend; e += 1024) {
        int2 ed = estage[e];
        int rl = ((unsigned)ed.x) >> 19;
        int pos = atomicAdd(&lcnt[rl], 1);
        epack[pos] = make_int2(ed.x & 0x7FFFF, ed.y);
    }
    if (b == 0 && tid == 0) rowptr[NN] = N_EDGES;
}

// ---------------- row-dot, bf16 gather ----------------
__device__ __forceinline__ float row_dot_bf(const int2* __restrict__ ep, int beg, int end,
                                            const unsigned short* __restrict__ E, int lane) {
    const long long* epl = (const long long*)ep;
    float acc = 0.f;
    int j = beg;
    int jend8 = beg + ((end - beg) & ~7);
    for (; j < jend8; j += 8) {
        long long d[8];
        #pragma unroll
        for (int k = 0; k < 8; ++k) d[k] = __builtin_nontemporal_load(&epl[j + k]);
        float x[8];
        #pragma unroll
        for (int k = 0; k < 8; ++k)
            x[k] = bf2f(E[(size_t)(int)(d[k] & 0x7FFFF) * DIM + lane]);
        #pragma unroll
        for (int k = 0; k < 8; ++k)
            acc = __builtin_fmaf(__int_as_float((int)(d[k] >> 32)), x[k], acc);
    }
    if (j + 4 <= end) {
        long long d[4];
        #pragma unroll
        for (int k = 0; k < 4; ++k) d[k] = __builtin_nontemporal_load(&epl[j + k]);
        float x[4];
        #pragma unroll
        for (int k = 0; k < 4; ++k)
            x[k] = bf2f(E[(size_t)(int)(d[k] & 0x7FFFF) * DIM + lane]);
        #pragma unroll
        for (int k = 0; k < 4; ++k)
            acc = __builtin_fmaf(__int_as_float((int)(d[k] >> 32)), x[k], acc);
        j += 4;
    }
    for (; j < end; ++j) {
        long long d = __builtin_nontemporal_load(&epl[j]);
        acc = __builtin_fmaf(__int_as_float((int)(d >> 32)),
                             bf2f(E[(size_t)(int)(d & 0x7FFFF) * DIM + lane]), acc);
    }
    return acc;
}

// ---------------- row-dot, fp8 gather (values pre-scaled by FP8SCALE) ----------------
__device__ __forceinline__ float row_dot_8(const int2* __restrict__ ep, int beg, int end,
                                           const unsigned char* __restrict__ E8, int lane) {
    const long long* epl = (const long long*)ep;
    float acc = 0.f;
    int j = beg;
    int jend8 = beg + ((end - beg) & ~7);
    for (; j < jend8; j += 8) {
        long long d[8];
        #pragma unroll
        for (int k = 0; k < 8; ++k) d[k] = __builtin_nontemporal_load(&epl[j + k]);
        float x[8];
        #pragma unroll
        for (int k = 0; k < 8; ++k)
            x[k] = fp82f(E8[(size_t)(int)(d[k] & 0x7FFFF) * DIM + lane]);
        #pragma unroll
        for (int k = 0; k < 8; ++k)
            acc = __builtin_fmaf(__int_as_float((int)(d[k] >> 32)), x[k], acc);
    }
    if (j + 4 <= end) {
        long long d[4];
        #pragma unroll
        for (int k = 0; k < 4; ++k) d[k] = __builtin_nontemporal_load(&epl[j + k]);
        float x[4];
        #pragma unroll
        for (int k = 0; k < 4; ++k)
            x[k] = fp82f(E8[(size_t)(int)(d[k] & 0x7FFFF) * DIM + lane]);
        #pragma unroll
        for (int k = 0; k < 4; ++k)
            acc = __builtin_fmaf(__int_as_float((int)(d[k] >> 32)), x[k], acc);
        j += 4;
    }
    for (; j < end; ++j) {
        long long d = __builtin_nontemporal_load(&epl[j]);
        acc = __builtin_fmaf(__int_as_float((int)(d >> 32)),
                             fp82f(E8[(size_t)(int)(d & 0x7FFFF) * DIM + lane]), acc);
    }
    return acc;   // caller applies FP8DESCALE where needed
}

// ---------------- layer 1: bf16 gather -> dual write (bf16 + fp8*SCALE) ----------------
__global__ void spmm_l1(const int* __restrict__ rowptr, const int2* __restrict__ ep,
                        const unsigned short* __restrict__ Ein,
                        unsigned short* __restrict__ Ebf,
                        unsigned char* __restrict__ E8) {
    int lane = threadIdx.x & 63;
    int w = (int)((blockIdx.x * (size_t)blockDim.x + threadIdx.x) >> 6);
    int row = __builtin_amdgcn_readfirstlane(w);
    if (row >= NN) return;
    int beg = rowptr[row];
    int end = rowptr[row + 1];
    float acc = row_dot_bf(ep, beg, end, Ein, lane);
    size_t idx = (size_t)row * DIM + lane;
    __builtin_nontemporal_store(f2bf(acc), &Ebf[idx]);
    __builtin_nontemporal_store(f2fp8(acc * FP8SCALE), &E8[idx]);
}

// ---------------- layer 2: fp8 gather -> dual write (acc is already SCALE*E2) ----------------
__global__ void spmm_l2(const int* __restrict__ rowptr, const int2* __restrict__ ep,
                        const unsigned char* __restrict__ Ein8,
                        unsigned short* __restrict__ Ebf,
                        unsigned char* __restrict__ E8) {
    int lane = threadIdx.x & 63;
    int w = (int)((blockIdx.x * (size_t)blockDim.x + threadIdx.x) >> 6);
    int row = __builtin_amdgcn_readfirstlane(w);
    if (row >= NN) return;
    int beg = rowptr[row];
    int end = rowptr[row + 1];
    float acc = row_dot_8(ep, beg, end, Ein8, lane);      // = SCALE * E2
    size_t idx = (size_t)row * DIM + lane;
    __builtin_nontemporal_store(f2bf(acc * FP8DESCALE), &Ebf[idx]);
    __builtin_nontemporal_store(f2fp8(acc), &E8[idx]);
}

// ---------------- layer 3: fp8 gather only at the 2*BATCH target rows, fused acc ----------------
__global__ void spmm_target(const int* __restrict__ rowptr, const int2* __restrict__ ep,
                            const unsigned char* __restrict__ Ein8,
                            const int* __restrict__ U, const int* __restrict__ I,
                            float* __restrict__ accU, float* __restrict__ accI) {
    int lane = threadIdx.x & 63;
    int w = (int)((blockIdx.x * (size_t)blockDim.x + threadIdx.x) >> 6);
    if (w >= 2 * BATCH) return;
    int row;
    float* accp;
    if (w < BATCH) { row = U[w];                   accp = accU + (size_t)w * DIM; }
    else           { row = N_USERS + I[w - BATCH]; accp = accI + (size_t)(w - BATCH) * DIM; }
    row = __builtin_amdgcn_readfirstlane(row);
    int beg = rowptr[row];
    int end = rowptr[row + 1];
    float acc = row_dot_8(ep, beg, end, Ein8, lane);      // = SCALE * E3
    accp[lane] += acc * FP8DESCALE;
}

// ---------------- acc at the 2*BATCH target rows ----------------
__global__ void acc_init(const float* __restrict__ ue, const float* __restrict__ ie,
                         const int* __restrict__ U, const int* __restrict__ I,
                         float* __restrict__ accU, float* __restrict__ accI) {
    int t = blockIdx.x * blockDim.x + threadIdx.x;
    int b = t >> 6, d = t & 63;
    accU[t] = ue[(size_t)U[b] * DIM + d];
    accI[t] = ie[(size_t)I[b] * DIM + d];
}

__global__ void acc_add(const unsigned short* __restrict__ E, const int* __restrict__ U,
                        const int* __restrict__ I, float* __restrict__ accU,
                        float* __restrict__ accI) {
    int t = blockIdx.x * blockDim.x + threadIdx.x;
    int b = t >> 6, d = t & 63;
    accU[t] += bf2f(E[(size_t)U[b] * DIM + d]);
    accI[t] += bf2f(E[(size_t)(N_USERS + I[b]) * DIM + d]);
}

// ---------------- final: out[b] = dot(accU[b], accI[b]) / 16 ----------------
__global__ void dot_out(const float* __restrict__ accU, const float* __restrict__ accI,
                        float* __restrict__ out) {
    int t = blockIdx.x * blockDim.x + threadIdx.x;
    int b = t >> 6, lane = threadIdx.x & 63;
    float p = accU[t] * accI[t];
    #pragma unroll
    for (int off = 32; off; off >>= 1) p += __shfl_xor(p, off, 64);
    if (lane == 0) out[b] = p * (1.0f / 16.0f);
}

extern "C" void kernel_launch(void* const* d_in, const int* in_sizes, int n_in,
                              void* d_out, int out_size, void* d_ws, size_t ws_size,
                              hipStream_t stream) {
    const float* ue   = (const float*)d_in[0];
    const float* ie   = (const float*)d_in[1];
    const float* vals = (const float*)d_in[2];
    const int*   rows = (const int*)d_in[3];
    const int*   cols = (const int*)d_in[4];
    const int*   U    = (const int*)d_in[5];
    const int*   I    = (const int*)d_in[6];
    float* out = (float*)d_out;

    char* ws = (char*)d_ws;
    const size_t EPbytes = (size_t)N_EDGES * sizeof(int2);            // 76.8 MB
    const size_t EBbytes = (size_t)NN * DIM * sizeof(unsigned short); // 38.4 MB
    const size_t E8bytes = (size_t)NN * DIM;                          // 19.2 MB
    const size_t ACbytes = (size_t)BATCH * DIM * sizeof(float);       // 4.2 MB
    const size_t RPbytes = ((size_t)(NN + 1) * sizeof(int) + 255) & ~(size_t)255;
    const size_t NBbytes = (((size_t)(NB2 + 1) * sizeof(int)) + 255) & ~(size_t)255;

    size_t off = 0;
    int2*  epack  = (int2*)(ws + off);                   off += EPbytes;
    unsigned short* Ebf_a = (unsigned short*)(ws + off); off += EBbytes;  // aliased by estage pre-to_bf16
    unsigned short* Ebf_b = (unsigned short*)(ws + off); off += EBbytes;
    unsigned char*  E8_a  = (unsigned char*)(ws + off);  off += E8bytes;
    unsigned char*  E8_b  = (unsigned char*)(ws + off);  off += E8bytes;
    float* accU   = (float*)(ws + off); off += ACbytes;
    float* accI   = (float*)(ws + off); off += ACbytes;
    int*   rowptr = (int*)(ws + off);   off += RPbytes;
    int*   bcnt   = (int*)(ws + off);   off += NBbytes;
    int*   bstart = (int*)(ws + off);   off += NBbytes;
    int*   gfill  = (int*)(ws + off);   off += NBbytes;

    // edge staging (8 B/edge) aliases Ebf_a+Ebf_b region (dead before to_bf16 runs)
    int2* estage = (int2*)Ebf_a;

    const int nBinBlocks = (N_EDGES + CHUNK2 - 1) / CHUNK2;           // 2344

    // --- build CSR ---
    hipMemsetAsync(bcnt, 0, (size_t)(NB2 + 1) * sizeof(int), stream);
    hist_buckets<<<1024, 256, 0, stream>>>(rows, bcnt);
    scan_buckets<<<1, 512, 0, stream>>>(bcnt, bstart, gfill);
    bin_sort<<<nBinBlocks, 256, 0, stream>>>(rows, cols, vals, gfill, estage);
    row_scatter<<<NB2, 1024, 0, stream>>>(bstart, estage, epack, rowptr);

    // --- bf16 embedding table (after estage is dead) + exact-f32 E0 term ---
    to_bf16<<<2048, 256, 0, stream>>>(ue, ie, Ebf_a);
    acc_init<<<BATCH * DIM / 256, 256, 0, stream>>>(ue, ie, U, I, accU, accI);

    const int spmmBlocks = (NN * 64 + 255) / 256;                     // 1 wave per row

    // layer 1: bf16 gather from Ebf_a -> (Ebf_b, E8_b)
    spmm_l1<<<spmmBlocks, 256, 0, stream>>>(rowptr, epack, Ebf_a, Ebf_b, E8_b);
    acc_add<<<BATCH * DIM / 256, 256, 0, stream>>>(Ebf_b, U, I, accU, accI);

    // layer 2: fp8 gather from E8_b -> (Ebf_a, E8_a)
    spmm_l2<<<spmmBlocks, 256, 0, stream>>>(rowptr, epack, E8_b, Ebf_a, E8_a);
    acc_add<<<BATCH * DIM / 256, 256, 0, stream>>>(Ebf_a, U, I, accU, accI);

    // layer 3: fp8 gather from E8_a, only at target rows, fused accumulate
    spmm_target<<<2 * BATCH * 64 / 256, 256, 0, stream>>>(rowptr, epack, E8_a, U, I, accU, accI);

    dot_out<<<BATCH / 4, 256, 0, stream>>>(accU, accI, out);
}